// Round 1
// 358.086 us; speedup vs baseline: 1.0918x; 1.0918x over previous
//
#include <hip/hip_runtime.h>
#include <cstddef>

// DIN attention, R5: latency-bound fix.
// - Setup kernel hoists all block-invariant weight work into d_ws:
//     qt[b,h]  = b1[h] + sum_k q[k]*(W1a+W1c)[k,h]          (f32, same loop order as R4)
//     wbc[s,j] = (W1b - W1c)[k,h], wd[s,j] = W1d[k,h]        (frag-slot-ordered f32)
//     w2a/w2b  = bf16 MFMA B-frags of w2 (K=0..63 full, K=64..79 tail)
// - Main kernel: Bwq = wbc + q*wd (coalesced), GEMM1 A-frags loaded global->reg
//   (no A-LDS staging, no per-kc barriers), wave-owned mt tiles so the hv
//   C->A transpose is wave-local. Layer2 K=80 exact (tail kstep lanes>=32 zero).
// - LDS 39.2KB -> 4 blocks/CU (was 51.7KB -> 3).

#define L_   200
#define D2_  128

typedef __attribute__((ext_vector_type(8))) short bf16x8;
typedef __attribute__((ext_vector_type(4))) float f32x4;
typedef __attribute__((ext_vector_type(4))) unsigned int u32x4;

union U8 { u32x4 u; bf16x8 b; };

__device__ __forceinline__ float sigmoidf_(float x) { return 1.0f / (1.0f + __expf(-x)); }

__device__ __forceinline__ unsigned int f2bf_(float x) {
  unsigned int u = __float_as_uint(x);
  return (u + 0x7fffu + ((u >> 16) & 1u)) >> 16;   // RNE, low 16 bits valid
}
__device__ __forceinline__ unsigned int pk2_(float a, float b) {
  return f2bf_(a) | (f2bf_(b) << 16);
}

// ---------------- setup: block-invariant precompute into ws ----------------
extern "C" __global__ void __launch_bounds__(128)
din_setup_kernel(const float* __restrict__ queries,
                 const float* __restrict__ w1,
                 const float* __restrict__ b1,
                 const float* __restrict__ w2,
                 float* __restrict__ qt,
                 float* __restrict__ wbc,
                 float* __restrict__ wd,
                 u32x4* __restrict__ w2a,
                 u32x4* __restrict__ w2b)
{
  const int bb = blockIdx.x;
  const int t  = threadIdx.x;

  if (bb < 8) {
    // Bwq operand split, frag-slot order: s = ((kc*5+nt)*4+kg)*16+n, 1280 slots
    for (int s = bb * 160 + t; s < bb * 160 + 160; s += 128) {
      int nn = s & 15, kg = (s >> 4) & 3, g = s >> 6;
      int kc = g / 5, nt = g - kc * 5;
      int h = nt * 16 + nn, k0 = kc * 32 + kg * 8;
      #pragma unroll
      for (int j = 0; j < 8; ++j) {
        int k = k0 + j;
        wbc[s * 8 + j] = w1[(128 + k) * 80 + h] - w1[(256 + k) * 80 + h];
        wd [s * 8 + j] = w1[(384 + k) * 80 + h];
      }
    }
  } else if (bb == 8) {
    // w2 B-frags, k 0..63: slot (nt2*8+kg)*16+n
    for (int s = t; s < 384; s += 128) {
      int nn = s & 15, g = s >> 4, nt2 = g >> 3, kg = g & 7;
      int j = nt2 * 16 + nn, k0 = kg * 8;
      u32x4 v = { 0u, 0u, 0u, 0u };
      if (j < 40) {
        float e0 = w2[(k0 + 0) * 40 + j], e1 = w2[(k0 + 1) * 40 + j];
        float e2 = w2[(k0 + 2) * 40 + j], e3 = w2[(k0 + 3) * 40 + j];
        float e4 = w2[(k0 + 4) * 40 + j], e5 = w2[(k0 + 5) * 40 + j];
        float e6 = w2[(k0 + 6) * 40 + j], e7 = w2[(k0 + 7) * 40 + j];
        v = (u32x4){ pk2_(e0, e1), pk2_(e2, e3), pk2_(e4, e5), pk2_(e6, e7) };
      }
      w2a[s] = v;
    }
    // w2 tail frags, k 64..79: slot (nt2*2+kgt)*16+n
    for (int s = t; s < 96; s += 128) {
      int nn = s & 15, g = s >> 4, nt2 = g >> 1, kgt = g & 1;
      int j = nt2 * 16 + nn, k0 = 64 + kgt * 8;
      u32x4 v = { 0u, 0u, 0u, 0u };
      if (j < 40) {
        float e0 = w2[(k0 + 0) * 40 + j], e1 = w2[(k0 + 1) * 40 + j];
        float e2 = w2[(k0 + 2) * 40 + j], e3 = w2[(k0 + 3) * 40 + j];
        float e4 = w2[(k0 + 4) * 40 + j], e5 = w2[(k0 + 5) * 40 + j];
        float e6 = w2[(k0 + 6) * 40 + j], e7 = w2[(k0 + 7) * 40 + j];
        v = (u32x4){ pk2_(e0, e1), pk2_(e2, e3), pk2_(e4, e5), pk2_(e6, e7) };
      }
      w2b[s] = v;
    }
  } else {
    // qt for one batch row (same math/order as the R4 in-kernel loop)
    const int b = bb - 9;
    __shared__ float qs[128];
    if (t < 128) qs[t] = queries[(size_t)b * D2_ + t];
    __syncthreads();
    if (t < 80) {
      float acc = b1[t];
      #pragma unroll 4
      for (int k = 0; k < 128; ++k)
        acc += qs[k] * (w1[k * 80 + t] + w1[(256 + k) * 80 + t]);
      qt[(size_t)b * 80 + t] = acc;
    }
  }
}

// ---------------- main kernel ----------------
extern "C" __global__ void __launch_bounds__(256, 4)
din_attn_kernel(const float* __restrict__ queries,
                const float* __restrict__ ub,
                const int*   __restrict__ masks,
                const float* __restrict__ b2,
                const float* __restrict__ w3,
                const float* __restrict__ qt,
                const float* __restrict__ wbc,
                const float* __restrict__ wd,
                const u32x4* __restrict__ w2a,
                const u32x4* __restrict__ w2b,
                float* __restrict__ out)
{
  // pool: Bwq frags (1280 slots = 20480B) during GEMM1,
  //       then hv A-frags (2080 slots = 33280B): k0..63 at slot 0..1663,
  //       k64..79 tail at slot 1664..2079 (slot = 16B).
  __shared__ __align__(16) char  pool[33280];
  __shared__ __align__(16) float wsum_s[1088];   // 8*136
  __shared__ __align__(16) float qt_s[80];
  __shared__ __align__(16) float b2_s[48];
  __shared__ __align__(16) float w3_s[48];
  __shared__ __align__(16) float scores_s[208];
  __shared__ float red_s[8];

  const int b    = blockIdx.x;
  const int t    = threadIdx.x;
  const int wave = t >> 6;
  const int lane = t & 63;
  const int n16  = lane & 15;
  const int rg   = lane >> 4;

  const float* ubbase = ub + (size_t)b * (L_ * D2_);
  const float* qrow   = queries + (size_t)b * D2_;

  if (t < 80) qt_s[t] = qt[(size_t)b * 80 + t];
  if (t < 48) {
    b2_s[t] = (t < 40) ? b2[t] : 0.0f;
    w3_s[t] = (t < 40) ? w3[t] : 0.0f;
  }

  // ---- Bwq build: wq = wbc + q*wd, all loads coalesced (ws is L2-resident) ----
  {
    u32x4* dst = (u32x4*)pool;
    const float4* wbc4 = (const float4*)wbc;
    const float4* wd4  = (const float4*)wd;
    #pragma unroll
    for (int i = 0; i < 5; ++i) {
      int s = i * 256 + t;                      // 0..1279
      int kg = (s >> 4) & 3, g = s >> 6;
      int kc = g / 5;
      int k0 = kc * 32 + kg * 8;
      float4 c0 = wbc4[2 * s], c1 = wbc4[2 * s + 1];
      float4 d0 = wd4 [2 * s], d1 = wd4 [2 * s + 1];
      float4 q0 = *(const float4*)(qrow + k0);
      float4 q1 = *(const float4*)(qrow + k0 + 4);
      dst[s] = (u32x4){ pk2_(c0.x + q0.x * d0.x, c0.y + q0.y * d0.y),
                        pk2_(c0.z + q0.z * d0.z, c0.w + q0.w * d0.w),
                        pk2_(c1.x + q1.x * d1.x, c1.y + q1.y * d1.y),
                        pk2_(c1.z + q1.z * d1.z, c1.w + q1.w * d1.w) };
    }
  }
  __syncthreads();

  // ---- GEMM1: wave w owns mt = w, w+4, w+8, (w+12). A direct global->reg. ----
  f32x4 acc[4][5];
  #pragma unroll
  for (int i = 0; i < 4; ++i)
    #pragma unroll
    for (int nt = 0; nt < 5; ++nt) acc[i][nt] = (f32x4){0.f, 0.f, 0.f, 0.f};

  const bf16x8* Bf = (const bf16x8*)pool;

  for (int kc = 0; kc < 4; ++kc) {
    bf16x8 bvv[5];
    #pragma unroll
    for (int nt = 0; nt < 5; ++nt) bvv[nt] = Bf[(kc * 5 + nt) * 64 + lane];
    #pragma unroll
    for (int i = 0; i < 4; ++i) {
      int mt = wave + i * 4;
      if (mt < 13) {
        int row = mt * 16 + n16;
        float4 u0 = make_float4(0.f, 0.f, 0.f, 0.f);
        float4 u1 = make_float4(0.f, 0.f, 0.f, 0.f);
        if (row < L_) {
          const float4* src = (const float4*)(ubbase + (size_t)row * D2_ + kc * 32 + rg * 8);
          u0 = src[0]; u1 = src[1];
        }
        U8 av;
        av.u = (u32x4){ pk2_(u0.x, u0.y), pk2_(u0.z, u0.w),
                        pk2_(u1.x, u1.y), pk2_(u1.z, u1.w) };
        #pragma unroll
        for (int nt = 0; nt < 5; ++nt)
          acc[i][nt] = __builtin_amdgcn_mfma_f32_16x16x32_bf16(av.b, bvv[nt], acc[i][nt], 0, 0, 0);
      }
    }
  }
  __syncthreads();   // all Bwq reads done; pool becomes hv

  // ---- epilogue1: hv = sigmoid(preact1) into wave-local A-frag slots ----
  {
    unsigned short* hv = (unsigned short*)pool;
    #pragma unroll
    for (int i = 0; i < 4; ++i) {
      int mt = wave + i * 4;
      if (mt < 13) {
        #pragma unroll
        for (int nt = 0; nt < 5; ++nt) {
          int h = nt * 16 + n16;
          float qtv = qt_s[h];
          int kg = h >> 3;
          int slotbase = (kg < 8) ? (mt * 8 + kg) : (1664 + mt * 2 + (kg - 8));
          #pragma unroll
          for (int r = 0; r < 4; ++r) {
            float x = acc[i][nt][r] + qtv;
            hv[(slotbase * 16 + rg * 4 + r) * 8 + (h & 7)] =
                (unsigned short)f2bf_(sigmoidf_(x));
          }
        }
      }
    }
  }
  // wave-local hv: same-wave ds_write -> ds_read, no barrier needed

  // ---- layer2 + epilogue2 (K=80: 2 full ksteps + half-populated tail) ----
  {
    const bf16x8* hvf  = (const bf16x8*)pool;
    const bf16x8* w2af = (const bf16x8*)w2a;
    const bf16x8* w2bf = (const bf16x8*)w2b;
    #pragma unroll
    for (int i = 0; i < 4; ++i) {
      int mt = wave + i * 4;
      if (mt < 13) {
        f32x4 acc2[3];
        #pragma unroll
        for (int n2 = 0; n2 < 3; ++n2) acc2[n2] = (f32x4){0.f, 0.f, 0.f, 0.f};

        #pragma unroll
        for (int ks = 0; ks < 2; ++ks) {
          bf16x8 av = hvf[(mt * 8 + ks * 4 + rg) * 16 + n16];
          #pragma unroll
          for (int n2 = 0; n2 < 3; ++n2) {
            bf16x8 bv = w2af[(n2 * 8 + ks * 4 + rg) * 16 + n16];
            acc2[n2] = __builtin_amdgcn_mfma_f32_16x16x32_bf16(av, bv, acc2[n2], 0, 0, 0);
          }
        }
        { // tail kstep: k 64..79 in lanes 0..31, upper half zero
          bf16x8 av = (bf16x8){0, 0, 0, 0, 0, 0, 0, 0};
          if (lane < 32) av = hvf[(1664 + mt * 2 + rg) * 16 + n16];
          #pragma unroll
          for (int n2 = 0; n2 < 3; ++n2) {
            bf16x8 bv = (bf16x8){0, 0, 0, 0, 0, 0, 0, 0};
            if (lane < 32) bv = w2bf[(n2 * 2 + rg) * 16 + n16];
            acc2[n2] = __builtin_amdgcn_mfma_f32_16x16x32_bf16(av, bv, acc2[n2], 0, 0, 0);
          }
        }

        #pragma unroll
        for (int r = 0; r < 4; ++r) {
          float s = 0.0f;
          #pragma unroll
          for (int n2 = 0; n2 < 3; ++n2) {
            int j = n2 * 16 + n16;
            s += sigmoidf_(acc2[n2][r] + b2_s[j]) * w3_s[j];
          }
          s += __shfl_xor(s, 1, 64);
          s += __shfl_xor(s, 2, 64);
          s += __shfl_xor(s, 4, 64);
          s += __shfl_xor(s, 8, 64);
          int l = mt * 16 + rg * 4 + r;
          if (n16 == 0 && l < L_) scores_s[l] = s;
        }
      }
    }
  }
  __syncthreads();

  // ---- masked softmax over L (b3 omitted: softmax shift-invariant) ----
  float sval = -INFINITY;
  if (t < L_) {
    int mv = masks[(size_t)b * L_ + t];
    sval = mv ? scores_s[t] : -4294967295.0f;  // NEG_LARGE
  }
  float m = sval;
  #pragma unroll
  for (int o = 32; o > 0; o >>= 1) m = fmaxf(m, __shfl_xor(m, o, 64));
  if (lane == 0) red_s[wave] = m;
  __syncthreads();
  m = fmaxf(fmaxf(red_s[0], red_s[1]), fmaxf(red_s[2], red_s[3]));
  float e = (t < L_) ? __expf(sval - m) : 0.0f;
  float ssum = e;
  #pragma unroll
  for (int o = 32; o > 0; o >>= 1) ssum += __shfl_xor(ssum, o, 64);
  if (lane == 0) red_s[4 + wave] = ssum;
  __syncthreads();
  ssum = red_s[4] + red_s[5] + red_s[6] + red_s[7];
  float attn = e / ssum;
  __syncthreads();
  if (t < L_) scores_s[t] = attn;
  __syncthreads();

  // ---- weighted sum: out[d] = sum_l attn[l]*ub[l,d] (fp32, float4) ----
  {
    const float4* ub4base = (const float4*)ubbase;
    int d4 = t & 31;
    int lg = t >> 5;
    float4 o = make_float4(0.f, 0.f, 0.f, 0.f);
    #pragma unroll 5
    for (int l = lg; l < L_; l += 8) {
      float w = scores_s[l];
      float4 v = ub4base[l * 32 + d4];
      o.x += w * v.x; o.y += w * v.y; o.z += w * v.z; o.w += w * v.w;
    }
    *(float4*)(wsum_s + lg * 136 + d4 * 4) = o;
    __syncthreads();
    if (t < 128) {
      float s = 0.0f;
      #pragma unroll
      for (int g = 0; g < 8; ++g) s += wsum_s[g * 136 + t];
      out[(size_t)b * 128 + t] = s;
    }
  }
}

extern "C" void kernel_launch(void* const* d_in, const int* in_sizes, int n_in,
                              void* d_out, int out_size, void* d_ws, size_t ws_size,
                              hipStream_t stream) {
  const float* queries = (const float*)d_in[0];
  const float* ub      = (const float*)d_in[1];
  const int*   masks   = (const int*)d_in[2];
  const float* w1      = (const float*)d_in[3];
  const float* b1      = (const float*)d_in[4];
  const float* w2      = (const float*)d_in[5];
  const float* b2      = (const float*)d_in[6];
  const float* w3      = (const float*)d_in[7];
  float* out = (float*)d_out;

  const int B = in_sizes[0] / D2_;   // 2048

  // ws layout (needs B*320 + 89600 B = 745 KB @ B=2048)
  char*  ws  = (char*)d_ws;
  float* qt  = (float*)ws;                                   // B*80 f32
  float* wbc = (float*)(ws + (size_t)B * 320);               // 1280*8 f32 = 40960B
  float* wd  = (float*)(ws + (size_t)B * 320 + 40960);       // 40960B
  u32x4* w2a = (u32x4*)(ws + (size_t)B * 320 + 81920);       // 384*16B = 6144B
  u32x4* w2b = (u32x4*)(ws + (size_t)B * 320 + 88064);       // 96*16B = 1536B

  din_setup_kernel<<<B + 9, 128, 0, stream>>>(queries, w1, b1, w2, qt, wbc, wd, w2a, w2b);
  din_attn_kernel<<<B, 256, 0, stream>>>(queries, ub, masks, b2, w3,
                                         qt, wbc, wd, w2a, w2b, out);
}